// Round 7
// baseline (8988.065 us; speedup 1.0000x reference)
//
#include <hip/hip_runtime.h>

// LSTM B=512, T=512, H=256. Round 23 = STRUCTURAL REWRITE: single-block
// groups, zero cross-block communication.
// Ledger: r16=995.7us (LLC handshake), r21=1590 (mixed L2/LLC), r22=1079
// (poll shaping; FETCH unchanged -> handshake is latency- not contention-
// bound). The 4-block group exists only because W_hh fp16 (512KB) exceeds
// LDS; it DOES fit LDS+VGPR of ONE CU. One block per group: 64 blocks x 512
// thr, 8 batches each, full H=256. All sync = __syncthreads. No spins, no
// flags, no gbuf, no memset, no finalize kernel. Deterministic.
// Weights (prescaled -log2e i,f,o / +2log2e g; prep_weights BYTE-IDENTICAL
// to r16): per wave 64 frags (2 col-subs x 4 gates x 8 kt). Reg tier kt 0..5
// = 48 frags = 192 VGPR (r16 asm-pin pattern, 8->48). LDS tier kt 6,7 = 128KB.
// LDS: wlds 128K + h_full[16][264] 8.4K (r16 layout) + wbl 8K = 144.5KB.
// Per step: 2 cp-passes {8x ds_read A + 32 MFMA + nonlin(quad<2)}; h16 held
// in regs; barrier; h-writes; barrier. Pass-2 A-reads precede b1 -> no race
// with h_t writes. cst/oacc in regs. Rows 8-15 of h stay zero (M=16 tile,
// 8 batches). Final: shfl-reduce oacc over l16, red overlays dead h_full,
// out[b0+m] = sum + b_out. MFMA f32_16x16x32_f16: A=h[m=l16][k=quad*8+j],
// B=W[k][n=l16], D[m=quad*4+r][n=l16] (r16-verified mapping).
// Predicted: dur 995 -> 350-500us; WRITE_SIZE 524MB -> <10MB; FETCH <100MB;
// VALUBusy up; MfmaUtil modest (64 CUs active). Worst case: VGPR spill ->
// passes but slower; counters will show it.

typedef _Float16 half8 __attribute__((ext_vector_type(8)));
typedef float f32x4 __attribute__((ext_vector_type(4)));
typedef float f32x2 __attribute__((ext_vector_type(2)));

constexpr int kT = 512;
constexpr int kHF = 264;   // h_full row stride (halves), r16-proven padding
constexpr float kLog2e = 1.44269504088896340736f;

// ws layout: [0, 524288) weight fragments fp16, frag (sub,c,g,kt) at half8
// idx (sub*128 + (c*4+g)*8 + kt)*64 + lane  (BYTE-IDENTICAL to r16)
__global__ void prep_weights(const float* __restrict__ W_hh, _Float16* __restrict__ ws)
{
    int gid = blockIdx.x * blockDim.x + threadIdx.x;  // 0..32767, one half8 each
    int lane = gid & 63;
    int f = (gid >> 6) & 127;
    int sub = gid >> 13;
    int kt = f & 7, g = (f >> 3) & 3, c = f >> 5;
    int R = g * 256 + sub * 64 + c * 16 + (lane & 15);
    int k = kt * 32 + (lane >> 4) * 8;
    float s = (g == 2) ? 2.0f * kLog2e : -kLog2e;
    const float* src = W_hh + R * 256 + k;
    half8 v;
    #pragma unroll
    for (int j = 0; j < 8; ++j) v[j] = (_Float16)(src[j] * s);
    reinterpret_cast<half8*>(ws)[gid] = v;
}

__global__ __launch_bounds__(512, 2)
void lstm_fused(const float* __restrict__ ts,
                const float* __restrict__ W_ih,
                const float* __restrict__ b_ih,
                const float* __restrict__ b_hh,
                const float* __restrict__ W_out,
                const float* __restrict__ b_out,
                const _Float16* __restrict__ wfrag,
                float* __restrict__ out)
{
    __shared__ __align__(16) _Float16 wlds[65536];      // 128 KB: kt 6,7 frags
    __shared__ __align__(16) _Float16 h_full[16][kHF];  // 8448 B (rows 8..15 stay 0)
    __shared__ __align__(16) float wbl[2048];           // 8 KB: (wih,bias) per (col,gate)

    const int tid  = threadIdx.x;
    const int w    = tid >> 6;      // wave 0..7, owns cols [w*32, w*32+32)
    const int lane = tid & 63;
    const int l16  = lane & 15;
    const int quad = lane >> 4;
    const int bid  = blockIdx.x;    // 0..63
    const int b0   = bid * 8;

    // wave w uses old-frag coords sub = w>>1, c = (w&1)*2 + cp
    const half8* wf8 = reinterpret_cast<const half8*>(wfrag) + (w >> 1) * 8192;
    half8* wl8 = reinterpret_cast<half8*>(wlds);

    // stage LDS weight tier (kt 6,7 for every wave): 8192 half8s
    for (int i = tid; i < 8192; i += 512) {
        int ln = i & 63, f = i >> 6;
        int ktb = f & 1, g = (f >> 1) & 3, cp = (f >> 3) & 1, wv = f >> 4;
        const half8* s8 = reinterpret_cast<const half8*>(wfrag) + (wv >> 1) * 8192;
        wl8[i] = s8[((((wv & 1) * 2 + cp) * 4 + g) * 8 + (6 + ktb)) * 64 + ln];
    }
    // zero h_full (h0 = 0; rows 8..15 permanently 0)
    for (int i = tid; i < 16 * kHF; i += 512) (&h_full[0][0])[i] = (_Float16)0.0f;
    // stage wih/bias table: e = (col*4+g)*2 + which
    for (int e = tid; e < 2048; e += 512) {
        int col = e >> 3, g = (e >> 1) & 3, which = e & 1;
        int R = g * 256 + col;
        float s = (g == 2) ? 2.0f * kLog2e : -kLog2e;
        wbl[e] = which ? (b_ih[R] + b_hh[R]) * s : W_ih[R] * s;
    }

    // ---- register weight tier: 48 frags (cp, g, kt 0..5) = 192 VGPR ----
    unsigned wr_[48][4];
    #pragma unroll
    for (int cp = 0; cp < 2; ++cp)
        #pragma unroll
        for (int g = 0; g < 4; ++g)
            #pragma unroll
            for (int kt = 0; kt < 6; ++kt) {
                uint4 v = *reinterpret_cast<const uint4*>(
                    &wf8[((((w & 1) * 2 + cp) * 4 + g) * 8 + kt) * 64 + lane]);
                int i = cp * 24 + g * 6 + kt;
                wr_[i][0] = v.x; wr_[i][1] = v.y; wr_[i][2] = v.z; wr_[i][3] = v.w;
                asm volatile("" : "+v"(wr_[i][0]), "+v"(wr_[i][1]),
                                  "+v"(wr_[i][2]), "+v"(wr_[i][3]));
            }

    float cst[2][4] = {{0.f,0.f,0.f,0.f},{0.f,0.f,0.f,0.f}};
    float oacc[4]   = {0.f,0.f,0.f,0.f};
    const int colb0 = w * 32 + l16;   // cp=0 column of this lane

    __syncthreads();

    for (int t = 0; t < kT; ++t) {
        // re-pin reg weight tier (r16-proven anti-remat/spill pattern)
        #pragma unroll
        for (int i = 0; i < 48; ++i)
            asm volatile("" : "+v"(wr_[i][0]), "+v"(wr_[i][1]),
                              "+v"(wr_[i][2]), "+v"(wr_[i][3]));

        float tsv[4] = {0.f,0.f,0.f,0.f};
        float wo[2]  = {0.f,0.f};
        if (quad < 2) {
            #pragma unroll
            for (int r = 0; r < 4; ++r)
                tsv[r] = ts[(b0 + quad * 4 + r) * kT + t];
            wo[0] = W_out[t * 256 + colb0];
            wo[1] = W_out[t * 256 + colb0 + 16];
        }

        _Float16 hv16[2][4];
        #pragma unroll
        for (int cp = 0; cp < 2; ++cp) {
            f32x4 gacc[4];
            #pragma unroll
            for (int g = 0; g < 4; ++g) { f32x4 z = {0.f,0.f,0.f,0.f}; gacc[g] = z; }
            #pragma unroll
            for (int kt = 0; kt < 8; ++kt) {
                half8 a = *reinterpret_cast<const half8*>(
                    &h_full[l16][kt * 32 + quad * 8]);
                #pragma unroll
                for (int g = 0; g < 4; ++g) {
                    half8 wv;
                    if (kt < 6) {
                        int i = cp * 24 + g * 6 + kt;
                        wv = __builtin_bit_cast(half8,
                            make_uint4(wr_[i][0], wr_[i][1], wr_[i][2], wr_[i][3]));
                    } else {
                        wv = wl8[(((w * 2 + cp) * 4 + g) * 2 + (kt - 6)) * 64 + lane];
                    }
                    gacc[g] = __builtin_amdgcn_mfma_f32_16x16x32_f16(a, wv, gacc[g], 0, 0, 0);
                }
            }
            if (quad < 2) {
                const int colb = colb0 + cp * 16;
                f32x2 wb[4];
                #pragma unroll
                for (int g = 0; g < 4; ++g)
                    wb[g] = *reinterpret_cast<const f32x2*>(&wbl[(colb * 4 + g) * 2]);
                #pragma unroll
                for (int r = 0; r < 4; ++r) {
                    float gi = gacc[0][r] + (tsv[r] * wb[0].x + wb[0].y);
                    float gf = gacc[1][r] + (tsv[r] * wb[1].x + wb[1].y);
                    float gg = gacc[2][r] + (tsv[r] * wb[2].x + wb[2].y);
                    float go = gacc[3][r] + (tsv[r] * wb[3].x + wb[3].y);
                    float I = __builtin_amdgcn_rcpf(1.0f + __builtin_amdgcn_exp2f(gi));
                    float F = __builtin_amdgcn_rcpf(1.0f + __builtin_amdgcn_exp2f(gf));
                    float G = 1.0f - 2.0f * __builtin_amdgcn_rcpf(1.0f + __builtin_amdgcn_exp2f(gg));
                    float O = __builtin_amdgcn_rcpf(1.0f + __builtin_amdgcn_exp2f(go));
                    float cn = F * cst[cp][r] + I * G;
                    cst[cp][r] = cn;
                    float tc = 1.0f - 2.0f * __builtin_amdgcn_rcpf(
                                   1.0f + __builtin_amdgcn_exp2f(2.0f * kLog2e * cn));
                    float hv = O * tc;
                    oacc[r] += hv * wo[cp];
                    hv16[cp][r] = (_Float16)hv;
                }
            }
        }
        __syncthreads();   // b1: every wave's A-reads of h_{t-1} are done
        if (quad < 2) {
            #pragma unroll
            for (int cp = 0; cp < 2; ++cp)
                #pragma unroll
                for (int r = 0; r < 4; ++r)
                    h_full[quad * 4 + r][colb0 + cp * 16] = hv16[cp][r];
        }
        __syncthreads();   // b2: h_t complete for next step's A-reads
    }

    // ---- output: reduce oacc over l16 (cols); red overlays dead h_full ----
    float* red = reinterpret_cast<float*>(&h_full[0][0]);
    #pragma unroll
    for (int r = 0; r < 4; ++r) {
        float v = oacc[r];
        v += __shfl_xor(v, 1, 64);
        v += __shfl_xor(v, 2, 64);
        v += __shfl_xor(v, 4, 64);
        v += __shfl_xor(v, 8, 64);
        if (l16 == 0 && quad < 2) red[w * 8 + quad * 4 + r] = v;
    }
    __syncthreads();
    if (tid < 8) {
        float s = b_out[0];
        #pragma unroll
        for (int wv = 0; wv < 8; ++wv) s += red[wv * 8 + tid];
        out[b0 + tid] = s;
    }
}

extern "C" void kernel_launch(void* const* d_in, const int* in_sizes, int n_in,
                              void* d_out, int out_size, void* d_ws, size_t ws_size,
                              hipStream_t stream) {
    const float* ts    = (const float*)d_in[0];
    const float* W_ih  = (const float*)d_in[1];
    const float* W_hh  = (const float*)d_in[2];
    const float* b_ih  = (const float*)d_in[3];
    const float* b_hh  = (const float*)d_in[4];
    const float* W_out = (const float*)d_in[5];
    const float* b_out = (const float*)d_in[6];

    _Float16* wfrag = (_Float16*)d_ws;   // 512 KB; no other workspace, no memset

    prep_weights<<<128, 256, 0, stream>>>(W_hh, wfrag);
    lstm_fused<<<64, 512, 0, stream>>>(ts, W_ih, b_ih, b_hh, W_out, b_out,
                                       wfrag, (float*)d_out);
}

// Round 8
// 4319.444 us; speedup vs baseline: 2.0808x; 2.0808x over previous
//
#include <hip/hip_runtime.h>

// LSTM B=512, T=512, H=256. Round 24 = r23 (verified single-block structure)
// re-planned at 4 waves/block so the weight register tier actually fits.
// r23 post-mortem: PASSED (absmax 2.4e-4 -> structure+math verified) but
// 8988us: VGPR_Count=128 proves the 192-VGPR pinned tier spilled to scratch
// (needed ~250/256 cap at 8 waves/CU; allocator refused) -> per-step scratch
// thrash (VALUBusy 2.7%, MfmaUtil 1.2%). Fix: 256 thr = 4 waves = 1 wave/SIMD
// -> 512-reg cap (m08: no spill through ~450). Tier = 96 frags (kt0..5 x
// 4cp x 4g) = 384 pinned VGPR + ~60 working ~= 445/512 (87% vs r23's 98%).
// LDS tier kt6,7 = 128KB. 64 blocks x 8 batches; wave owns 64 cols (4 cp).
// Pure relabel of r23's verified mapping: old w8 = 2*w4+(cp4>>1), c = cp4;
// frag idx ((cp*4+g)*8+kt), colb0 = w*64+l16, h-write rows quad*4+r — all
// carried over unchanged. prep_weights BYTE-IDENTICAL (r16/r23-verified).
// Per step: 8 A ds_reads + 32 LDS W reads (~480cyc LDS pipe) || 128 MFMA
// (~640cyc MFMA pipe) || nonlin (~600cyc VALU, cp-overlapped) + 2 barriers
// ~= 1100-1400 cyc/step -> ~250-400us total.
// No cross-block traffic: no gbuf/memset/finalize. All sync = __syncthreads.
// Predicted: VGPR_Count 420-500 (success signal), dur 300-500us, WRITE<5MB,
// FETCH<50MB. If VGPR<=256 + ms-range dur: allocator failed again -> next
// round falls back to 2-block groups (64-VGPR tier).

typedef _Float16 half8 __attribute__((ext_vector_type(8)));
typedef float f32x4 __attribute__((ext_vector_type(4)));
typedef float f32x2 __attribute__((ext_vector_type(2)));

constexpr int kT = 512;
constexpr int kHF = 264;   // h_full row stride (halves), r16-proven padding
constexpr float kLog2e = 1.44269504088896340736f;

// ws layout: [0, 524288) weight fragments fp16, frag (sub,c,g,kt) at half8
// idx (sub*128 + (c*4+g)*8 + kt)*64 + lane  (BYTE-IDENTICAL to r16/r23)
__global__ void prep_weights(const float* __restrict__ W_hh, _Float16* __restrict__ ws)
{
    int gid = blockIdx.x * blockDim.x + threadIdx.x;  // 0..32767, one half8 each
    int lane = gid & 63;
    int f = (gid >> 6) & 127;
    int sub = gid >> 13;
    int kt = f & 7, g = (f >> 3) & 3, c = f >> 5;
    int R = g * 256 + sub * 64 + c * 16 + (lane & 15);
    int k = kt * 32 + (lane >> 4) * 8;
    float s = (g == 2) ? 2.0f * kLog2e : -kLog2e;
    const float* src = W_hh + R * 256 + k;
    half8 v;
    #pragma unroll
    for (int j = 0; j < 8; ++j) v[j] = (_Float16)(src[j] * s);
    reinterpret_cast<half8*>(ws)[gid] = v;
}

__global__ __launch_bounds__(256, 1)
void lstm_fused(const float* __restrict__ ts,
                const float* __restrict__ W_ih,
                const float* __restrict__ b_ih,
                const float* __restrict__ b_hh,
                const float* __restrict__ W_out,
                const float* __restrict__ b_out,
                const _Float16* __restrict__ wfrag,
                float* __restrict__ out)
{
    __shared__ __align__(16) _Float16 wlds[65536];      // 128 KB: kt 6,7 frags
    __shared__ __align__(16) _Float16 h_full[16][kHF];  // 8448 B (rows 8..15 stay 0)
    __shared__ __align__(16) float wbl[2048];           // 8 KB: (wih,bias) per (col,gate)

    const int tid  = threadIdx.x;
    const int w    = tid >> 6;      // wave 0..3, owns cols [w*64, w*64+64)
    const int lane = tid & 63;
    const int l16  = lane & 15;
    const int quad = lane >> 4;
    const int bid  = blockIdx.x;    // 0..63
    const int b0   = bid * 8;

    // wave w == old frag sub; cp (0..3) == old frag c
    const half8* wf8 = reinterpret_cast<const half8*>(wfrag) + w * 8192;
    half8* wl8 = reinterpret_cast<half8*>(wlds);

    // stage LDS weight tier (kt 6,7 for all subs): 8192 half8s
    // dst f = wv*32 + c*8 + g*2 + ktb
    for (int i = tid; i < 8192; i += 256) {
        int ln = i & 63, f = i >> 6;
        int ktb = f & 1, g = (f >> 1) & 3, c = (f >> 3) & 3, wv = (f >> 5) & 3;
        const half8* s8 = reinterpret_cast<const half8*>(wfrag) + wv * 8192;
        wl8[i] = s8[((c * 4 + g) * 8 + 6 + ktb) * 64 + ln];
    }
    // zero h_full (h0 = 0; rows 8..15 permanently 0)
    for (int i = tid; i < 16 * kHF; i += 256) (&h_full[0][0])[i] = (_Float16)0.0f;
    // stage wih/bias table: e = (col*4+g)*2 + which
    for (int e = tid; e < 2048; e += 256) {
        int col = e >> 3, g = (e >> 1) & 3, which = e & 1;
        int R = g * 256 + col;
        float s = (g == 2) ? 2.0f * kLog2e : -kLog2e;
        wbl[e] = which ? (b_ih[R] + b_hh[R]) * s : W_ih[R] * s;
    }

    // ---- register weight tier: 96 frags (cp 0..3, g 0..3, kt 0..5) = 384 VGPR
    unsigned wr_[96][4];
    #pragma unroll
    for (int cp = 0; cp < 4; ++cp)
        #pragma unroll
        for (int g = 0; g < 4; ++g)
            #pragma unroll
            for (int kt = 0; kt < 6; ++kt) {
                uint4 v = *reinterpret_cast<const uint4*>(
                    &wf8[((cp * 4 + g) * 8 + kt) * 64 + lane]);
                int i = cp * 24 + g * 6 + kt;
                wr_[i][0] = v.x; wr_[i][1] = v.y; wr_[i][2] = v.z; wr_[i][3] = v.w;
                asm volatile("" : "+v"(wr_[i][0]), "+v"(wr_[i][1]),
                                  "+v"(wr_[i][2]), "+v"(wr_[i][3]));
            }

    float cst[4][4] = {{0.f,0.f,0.f,0.f},{0.f,0.f,0.f,0.f},
                       {0.f,0.f,0.f,0.f},{0.f,0.f,0.f,0.f}};
    float oacc[4]   = {0.f,0.f,0.f,0.f};
    const int colb0 = w * 64 + l16;   // cp=0 column of this lane

    __syncthreads();

    for (int t = 0; t < kT; ++t) {
        // re-pin reg weight tier (empty asm: constraints only, no code)
        #pragma unroll
        for (int i = 0; i < 96; ++i)
            asm volatile("" : "+v"(wr_[i][0]), "+v"(wr_[i][1]),
                              "+v"(wr_[i][2]), "+v"(wr_[i][3]));

        float tsv[4] = {0.f,0.f,0.f,0.f};
        float wo[4]  = {0.f,0.f,0.f,0.f};
        if (quad < 2) {
            #pragma unroll
            for (int r = 0; r < 4; ++r)
                tsv[r] = ts[(b0 + quad * 4 + r) * kT + t];
            #pragma unroll
            for (int cp = 0; cp < 4; ++cp)
                wo[cp] = W_out[t * 256 + colb0 + cp * 16];
        }

        // prefetch all 8 A fragments (shared across cp, g)
        half8 afr[8];
        #pragma unroll
        for (int kt = 0; kt < 8; ++kt)
            afr[kt] = *reinterpret_cast<const half8*>(
                &h_full[l16][kt * 32 + quad * 8]);

        _Float16 hv16[4][4];
        #pragma unroll
        for (int cp = 0; cp < 4; ++cp) {
            f32x4 gacc[4];
            #pragma unroll
            for (int g = 0; g < 4; ++g) { f32x4 z = {0.f,0.f,0.f,0.f}; gacc[g] = z; }
            #pragma unroll
            for (int kt = 0; kt < 8; ++kt) {
                #pragma unroll
                for (int g = 0; g < 4; ++g) {
                    half8 wv;
                    if (kt < 6) {
                        int i = cp * 24 + g * 6 + kt;
                        wv = __builtin_bit_cast(half8,
                            make_uint4(wr_[i][0], wr_[i][1], wr_[i][2], wr_[i][3]));
                    } else {
                        wv = wl8[(w * 32 + cp * 8 + g * 2 + (kt - 6)) * 64 + lane];
                    }
                    gacc[g] = __builtin_amdgcn_mfma_f32_16x16x32_f16(afr[kt], wv, gacc[g], 0, 0, 0);
                }
            }
            if (quad < 2) {
                const int colb = colb0 + cp * 16;
                f32x2 wb[4];
                #pragma unroll
                for (int g = 0; g < 4; ++g)
                    wb[g] = *reinterpret_cast<const f32x2*>(&wbl[(colb * 4 + g) * 2]);
                #pragma unroll
                for (int r = 0; r < 4; ++r) {
                    float gi = gacc[0][r] + (tsv[r] * wb[0].x + wb[0].y);
                    float gf = gacc[1][r] + (tsv[r] * wb[1].x + wb[1].y);
                    float gg = gacc[2][r] + (tsv[r] * wb[2].x + wb[2].y);
                    float go = gacc[3][r] + (tsv[r] * wb[3].x + wb[3].y);
                    float I = __builtin_amdgcn_rcpf(1.0f + __builtin_amdgcn_exp2f(gi));
                    float F = __builtin_amdgcn_rcpf(1.0f + __builtin_amdgcn_exp2f(gf));
                    float G = 1.0f - 2.0f * __builtin_amdgcn_rcpf(1.0f + __builtin_amdgcn_exp2f(gg));
                    float O = __builtin_amdgcn_rcpf(1.0f + __builtin_amdgcn_exp2f(go));
                    float cn = F * cst[cp][r] + I * G;
                    cst[cp][r] = cn;
                    float tc = 1.0f - 2.0f * __builtin_amdgcn_rcpf(
                                   1.0f + __builtin_amdgcn_exp2f(2.0f * kLog2e * cn));
                    float hv = O * tc;
                    oacc[r] += hv * wo[cp];
                    hv16[cp][r] = (_Float16)hv;
                }
            }
        }
        __syncthreads();   // b1: every wave's A-reads of h_{t-1} are done
        if (quad < 2) {
            #pragma unroll
            for (int cp = 0; cp < 4; ++cp)
                #pragma unroll
                for (int r = 0; r < 4; ++r)
                    h_full[quad * 4 + r][colb0 + cp * 16] = hv16[cp][r];
        }
        __syncthreads();   // b2: h_t complete for next step's A-reads
    }

    // ---- output: reduce oacc over l16 (cols); red overlays dead h_full ----
    float* red = reinterpret_cast<float*>(&h_full[0][0]);
    #pragma unroll
    for (int r = 0; r < 4; ++r) {
        float v = oacc[r];
        v += __shfl_xor(v, 1, 64);
        v += __shfl_xor(v, 2, 64);
        v += __shfl_xor(v, 4, 64);
        v += __shfl_xor(v, 8, 64);
        if (l16 == 0 && quad < 2) red[w * 8 + quad * 4 + r] = v;
    }
    __syncthreads();
    if (tid < 8) {
        float s = b_out[0];
        #pragma unroll
        for (int wv = 0; wv < 4; ++wv) s += red[wv * 8 + tid];
        out[b0 + tid] = s;
    }
}

extern "C" void kernel_launch(void* const* d_in, const int* in_sizes, int n_in,
                              void* d_out, int out_size, void* d_ws, size_t ws_size,
                              hipStream_t stream) {
    const float* ts    = (const float*)d_in[0];
    const float* W_ih  = (const float*)d_in[1];
    const float* W_hh  = (const float*)d_in[2];
    const float* b_ih  = (const float*)d_in[3];
    const float* b_hh  = (const float*)d_in[4];
    const float* W_out = (const float*)d_in[5];
    const float* b_out = (const float*)d_in[6];

    _Float16* wfrag = (_Float16*)d_ws;   // 512 KB; no other workspace, no memset

    prep_weights<<<128, 256, 0, stream>>>(W_hh, wfrag);
    lstm_fused<<<64, 256, 0, stream>>>(ts, W_ih, b_ih, b_hh, W_out, b_out,
                                       wfrag, (float*)d_out);
}

// Round 10
// 1922.099 us; speedup vs baseline: 4.6762x; 2.2473x over previous
//
#include <hip/hip_runtime.h>

// LSTM B=512, T=512, H=256. Round 26 = r24 (verified numerics) with the
// weight tier split across AGPR/VGPR via CONSTRAINT PINS ONLY — no hand asm.
// r25 post-mortem: FAILED absmax 1.3e-2 (and a 468.0 read elsewhere -> non-
// deterministic) — the hand-written v_mfma inline asm hit a gfx950 hazard
// the compiler couldn't see (opaque asm defeats the hazard recognizer).
// Index audit: every (cp,g,kt) term used exactly once -> plan right, asm
// execution wrong. Lesson: reach the register file through constraints, let
// builtins own the hazards.
// r24 post-mortem recap: VGPR_Count=256 == ArchVGPR class cap; "+v"-pinned
// 384-reg tier spilled ~220 regs to scratch -> 4319us. gfx950 MFMA builtins
// take AV-class operands (VGPR or AGPR) -> empty-asm "+a" pins park weight
// frags in AGPRs and builtins consume them DIRECTLY, zero copies, compiler-
// managed waits.
// Tier: wa_ 60 frags kt0..3 (all cp,g except cp3,g3) "+a" = 240/256 AGPR;
// wv_ 36 frags (kt4,5 all cp,g + displaced cp3,g3 kt0..3) "+v" = 144 v;
// working ~100 -> ~248/256 ArchVGPR (afr/gacc are AV-eligible slack).
// LDS tier kt6,7 = 128KB (verified staging). kt loop restored to r24's exact
// 0->7 order -> accumulation chain SSA-identical to r24 -> expect absmax
// 2.44e-4 reproduced.
// Everything else byte-r24: 64 blocks x 256 thr (4 waves, 1/SIMD), 8 batches
// per block, 2 barriers/step, no gbuf/memset/finalize; prep_weights BYTE-
// IDENTICAL (r16/r23/r24-verified).
// Predicted: PASS at ~2.4e-4; dur 250-450us if AGPR-direct works (VALUBusy
// 15-30%, MfmaUtil 5-12%, no 34ms cold dispatch); ~600-900us if a->v copies;
// ms-range + spill -> single-CU arc closes, fall back to 2-block groups.

typedef _Float16 half8 __attribute__((ext_vector_type(8)));
typedef float f32x4 __attribute__((ext_vector_type(4)));
typedef float f32x2 __attribute__((ext_vector_type(2)));

constexpr int kT = 512;
constexpr int kHF = 264;   // h_full row stride (halves), r16-proven padding
constexpr float kLog2e = 1.44269504088896340736f;

// ws layout: [0, 524288) weight fragments fp16, frag (sub,c,g,kt) at half8
// idx (sub*128 + (c*4+g)*8 + kt)*64 + lane  (BYTE-IDENTICAL to r16/r23/r24)
__global__ void prep_weights(const float* __restrict__ W_hh, _Float16* __restrict__ ws)
{
    int gid = blockIdx.x * blockDim.x + threadIdx.x;  // 0..32767, one half8 each
    int lane = gid & 63;
    int f = (gid >> 6) & 127;
    int sub = gid >> 13;
    int kt = f & 7, g = (f >> 3) & 3, c = f >> 5;
    int R = g * 256 + sub * 64 + c * 16 + (lane & 15);
    int k = kt * 32 + (lane >> 4) * 8;
    float s = (g == 2) ? 2.0f * kLog2e : -kLog2e;
    const float* src = W_hh + R * 256 + k;
    half8 v;
    #pragma unroll
    for (int j = 0; j < 8; ++j) v[j] = (_Float16)(src[j] * s);
    reinterpret_cast<half8*>(ws)[gid] = v;
}

__device__ __forceinline__ f32x4 mfma16(half8 a, half8 b, f32x4 c) {
    return __builtin_amdgcn_mfma_f32_16x16x32_f16(a, b, c, 0, 0, 0);
}

__global__ __launch_bounds__(256, 1)
void lstm_fused(const float* __restrict__ ts,
                const float* __restrict__ W_ih,
                const float* __restrict__ b_ih,
                const float* __restrict__ b_hh,
                const float* __restrict__ W_out,
                const float* __restrict__ b_out,
                const _Float16* __restrict__ wfrag,
                float* __restrict__ out)
{
    __shared__ __align__(16) _Float16 wlds[65536];      // 128 KB: kt 6,7 frags
    __shared__ __align__(16) _Float16 h_full[16][kHF];  // 8448 B (rows 8..15 stay 0)
    __shared__ __align__(16) float wbl[2048];           // 8 KB: (wih,bias) per (col,gate)

    const int tid  = threadIdx.x;
    const int w    = tid >> 6;      // wave 0..3, owns cols [w*64, w*64+64)
    const int lane = tid & 63;
    const int l16  = lane & 15;
    const int quad = lane >> 4;
    const int bid  = blockIdx.x;    // 0..63
    const int b0   = bid * 8;

    const half8* wf8 = reinterpret_cast<const half8*>(wfrag) + w * 8192;
    half8* wl8 = reinterpret_cast<half8*>(wlds);

    // stage LDS weight tier (kt 6,7 for all subs): dst f = wv*32+c*8+g*2+ktb
    for (int i = tid; i < 8192; i += 256) {
        int ln = i & 63, f = i >> 6;
        int ktb = f & 1, g = (f >> 1) & 3, c = (f >> 3) & 3, wv = (f >> 5) & 3;
        const half8* s8 = reinterpret_cast<const half8*>(wfrag) + wv * 8192;
        wl8[i] = s8[((c * 4 + g) * 8 + 6 + ktb) * 64 + ln];
    }
    // zero h_full (h0 = 0; rows 8..15 permanently 0)
    for (int i = tid; i < 16 * kHF; i += 256) (&h_full[0][0])[i] = (_Float16)0.0f;
    // stage wih/bias table: e = (col*4+g)*2 + which
    for (int e = tid; e < 2048; e += 256) {
        int col = e >> 3, g = (e >> 1) & 3, which = e & 1;
        int R = g * 256 + col;
        float s = (g == 2) ? 2.0f * kLog2e : -kLog2e;
        wbl[e] = which ? (b_ih[R] + b_hh[R]) * s : W_ih[R] * s;
    }

    // ---- AGPR tier: 60 frags (kt 0..3, all cp,g except cp3,g3), "+a" pins ----
    half8 wa_[60];
    #pragma unroll
    for (int cp = 0; cp < 4; ++cp)
        #pragma unroll
        for (int g = 0; g < 4; ++g) {
            if (cp == 3 && g == 3) continue;
            #pragma unroll
            for (int kt = 0; kt < 4; ++kt) {
                int i = cp * 16 + g * 4 + kt;   // 0..59
                wa_[i] = wf8[((cp * 4 + g) * 8 + kt) * 64 + lane];
                asm volatile("" : "+a"(wa_[i]));
            }
        }
    // ---- VGPR tier: 36 frags, "+v" pins ----
    // iv 0..31: (cp,g,kt4+ktb) = cp*8+g*2+ktb; iv 32..35: cp3,g3,kt0..3
    half8 wv_[36];
    #pragma unroll
    for (int cp = 0; cp < 4; ++cp)
        #pragma unroll
        for (int g = 0; g < 4; ++g)
            #pragma unroll
            for (int ktb = 0; ktb < 2; ++ktb) {
                int i = cp * 8 + g * 2 + ktb;
                wv_[i] = wf8[((cp * 4 + g) * 8 + 4 + ktb) * 64 + lane];
                asm volatile("" : "+v"(wv_[i]));
            }
    #pragma unroll
    for (int kt = 0; kt < 4; ++kt) {
        wv_[32 + kt] = wf8[((3 * 4 + 3) * 8 + kt) * 64 + lane];
        asm volatile("" : "+v"(wv_[32 + kt]));
    }

    float cst[4][4] = {{0.f,0.f,0.f,0.f},{0.f,0.f,0.f,0.f},
                       {0.f,0.f,0.f,0.f},{0.f,0.f,0.f,0.f}};
    float oacc[4]   = {0.f,0.f,0.f,0.f};
    const int colb0 = w * 64 + l16;   // cp=0 column of this lane

    __syncthreads();

    for (int t = 0; t < kT; ++t) {
        // re-pin both tiers (empty asm: constraints only, no code)
        #pragma unroll
        for (int i = 0; i < 60; ++i) asm volatile("" : "+a"(wa_[i]));
        #pragma unroll
        for (int i = 0; i < 36; ++i) asm volatile("" : "+v"(wv_[i]));

        float tsv[4] = {0.f,0.f,0.f,0.f};
        float wo[4]  = {0.f,0.f,0.f,0.f};
        if (quad < 2) {
            #pragma unroll
            for (int r = 0; r < 4; ++r)
                tsv[r] = ts[(b0 + quad * 4 + r) * kT + t];
            #pragma unroll
            for (int cp = 0; cp < 4; ++cp)
                wo[cp] = W_out[t * 256 + colb0 + cp * 16];
        }

        // prefetch all 8 A fragments (shared across cp, g)
        half8 afr[8];
        #pragma unroll
        for (int kt = 0; kt < 8; ++kt)
            afr[kt] = *reinterpret_cast<const half8*>(
                &h_full[l16][kt * 32 + quad * 8]);

        _Float16 hv16[4][4];
        #pragma unroll
        for (int cp = 0; cp < 4; ++cp) {
            f32x4 gacc[4];
            #pragma unroll
            for (int g = 0; g < 4; ++g) { f32x4 z = {0.f,0.f,0.f,0.f}; gacc[g] = z; }
            // r24's exact kt 0..7 order; W(kt) selected from wa_/wv_/wlds.
            #pragma unroll
            for (int kt = 0; kt < 8; ++kt) {
                #pragma unroll
                for (int g = 0; g < 4; ++g) {
                    half8 wv;
                    if (kt < 4) {
                        wv = (cp == 3 && g == 3) ? wv_[32 + kt]
                                                 : wa_[cp * 16 + g * 4 + kt];
                    } else if (kt < 6) {
                        wv = wv_[cp * 8 + g * 2 + (kt - 4)];
                    } else {
                        wv = wl8[(w * 32 + cp * 8 + g * 2 + (kt - 6)) * 64 + lane];
                    }
                    gacc[g] = mfma16(afr[kt], wv, gacc[g]);
                }
            }
            if (quad < 2) {
                const int colb = colb0 + cp * 16;
                f32x2 wb[4];
                #pragma unroll
                for (int g = 0; g < 4; ++g)
                    wb[g] = *reinterpret_cast<const f32x2*>(&wbl[(colb * 4 + g) * 2]);
                #pragma unroll
                for (int r = 0; r < 4; ++r) {
                    float gi = gacc[0][r] + (tsv[r] * wb[0].x + wb[0].y);
                    float gf = gacc[1][r] + (tsv[r] * wb[1].x + wb[1].y);
                    float gg = gacc[2][r] + (tsv[r] * wb[2].x + wb[2].y);
                    float go = gacc[3][r] + (tsv[r] * wb[3].x + wb[3].y);
                    float I = __builtin_amdgcn_rcpf(1.0f + __builtin_amdgcn_exp2f(gi));
                    float F = __builtin_amdgcn_rcpf(1.0f + __builtin_amdgcn_exp2f(gf));
                    float G = 1.0f - 2.0f * __builtin_amdgcn_rcpf(1.0f + __builtin_amdgcn_exp2f(gg));
                    float O = __builtin_amdgcn_rcpf(1.0f + __builtin_amdgcn_exp2f(go));
                    float cn = F * cst[cp][r] + I * G;
                    cst[cp][r] = cn;
                    float tc = 1.0f - 2.0f * __builtin_amdgcn_rcpf(
                                   1.0f + __builtin_amdgcn_exp2f(2.0f * kLog2e * cn));
                    float hv = O * tc;
                    oacc[r] += hv * wo[cp];
                    hv16[cp][r] = (_Float16)hv;
                }
            }
        }
        __syncthreads();   // b1: every wave's A-reads of h_{t-1} are done
        if (quad < 2) {
            #pragma unroll
            for (int cp = 0; cp < 4; ++cp)
                #pragma unroll
                for (int r = 0; r < 4; ++r)
                    h_full[quad * 4 + r][colb0 + cp * 16] = hv16[cp][r];
        }
        __syncthreads();   // b2: h_t complete for next step's A-reads
    }

    // ---- output: reduce oacc over l16 (cols); red overlays dead h_full ----
    float* red = reinterpret_cast<float*>(&h_full[0][0]);
    #pragma unroll
    for (int r = 0; r < 4; ++r) {
        float v = oacc[r];
        v += __shfl_xor(v, 1, 64);
        v += __shfl_xor(v, 2, 64);
        v += __shfl_xor(v, 4, 64);
        v += __shfl_xor(v, 8, 64);
        if (l16 == 0 && quad < 2) red[w * 8 + quad * 4 + r] = v;
    }
    __syncthreads();
    if (tid < 8) {
        float s = b_out[0];
        #pragma unroll
        for (int wv = 0; wv < 4; ++wv) s += red[wv * 8 + tid];
        out[b0 + tid] = s;
    }
}

extern "C" void kernel_launch(void* const* d_in, const int* in_sizes, int n_in,
                              void* d_out, int out_size, void* d_ws, size_t ws_size,
                              hipStream_t stream) {
    const float* ts    = (const float*)d_in[0];
    const float* W_ih  = (const float*)d_in[1];
    const float* W_hh  = (const float*)d_in[2];
    const float* b_ih  = (const float*)d_in[3];
    const float* b_hh  = (const float*)d_in[4];
    const float* W_out = (const float*)d_in[5];
    const float* b_out = (const float*)d_in[6];

    _Float16* wfrag = (_Float16*)d_ws;   // 512 KB; no other workspace, no memset

    prep_weights<<<128, 256, 0, stream>>>(W_hh, wfrag);
    lstm_fused<<<64, 256, 0, stream>>>(ts, W_ih, b_ih, b_hh, W_out, b_out,
                                       wfrag, (float*)d_out);
}

// Round 11
// 1854.422 us; speedup vs baseline: 4.8468x; 1.0365x over previous
//
#include <hip/hip_runtime.h>

// LSTM B=512, T=512, H=256. Round 27 = r26 with the register tier pushed to
// the FULL AGPR file: wa_ = 64 frags (kt0..3, ALL cp,g) = 256 AGPRs exactly;
// wv_ = 32 frags (kt4,5) = 128 VGPRs; LDS tier kt6,7 unchanged (128KB).
// r26 post-mortem: PASS 1922us absmax 2.44e-4, but VGPR_Count=256 (ArchVGPR
// cap) again. Ledger r24 (384v, spill, 4319) -> r26 (240a+144v, 1922) proves
// ArchVGPR pressure is THE lever. r26 demand: 144 tier + 32 afr + 16 gacc +
// ~80 misc ~= 273 > 256 -> residual shuffle/spill (L1/L2-resident, invisible
// in FETCH, ~1000s cyc/step exposed at 1 wave/SIMD). r27 demand: 128 + 32 +
// 16 + ~70 ~= 246 <= 256 — first config with real slack. Also deletes the
// cp3,g3 special case (r26's displaced frags join the a-tier).
// Everything else byte-r26: 64 blocks x 256 thr (4 waves, 1/SIMD), 8 batches
// per block, kt 0->7 accumulation order (SSA-identical numerics, expect
// absmax 2.44e-4), 2 barriers/step, no gbuf/memset/finalize; prep_weights
// BYTE-IDENTICAL (r16/r23/r24/r26-verified).
// Success signal: VGPR_Count < 256. Predicted dur 1922 -> 550-800us
// (MfmaUtil 8-12%, VALUBusy 12-18%, FETCH/WRITE unchanged ~5MB/1.7MB).
// If VGPR=256 & ~1900 still: v-pressure is structural (a->v copies?) ->
// next round probes tier rebalance. If pass fast: next round pipelines
// MFMA(cp+1) || nonlin(cp).

typedef _Float16 half8 __attribute__((ext_vector_type(8)));
typedef float f32x4 __attribute__((ext_vector_type(4)));
typedef float f32x2 __attribute__((ext_vector_type(2)));

constexpr int kT = 512;
constexpr int kHF = 264;   // h_full row stride (halves), r16-proven padding
constexpr float kLog2e = 1.44269504088896340736f;

// ws layout: [0, 524288) weight fragments fp16, frag (sub,c,g,kt) at half8
// idx (sub*128 + (c*4+g)*8 + kt)*64 + lane  (BYTE-IDENTICAL to r16..r26)
__global__ void prep_weights(const float* __restrict__ W_hh, _Float16* __restrict__ ws)
{
    int gid = blockIdx.x * blockDim.x + threadIdx.x;  // 0..32767, one half8 each
    int lane = gid & 63;
    int f = (gid >> 6) & 127;
    int sub = gid >> 13;
    int kt = f & 7, g = (f >> 3) & 3, c = f >> 5;
    int R = g * 256 + sub * 64 + c * 16 + (lane & 15);
    int k = kt * 32 + (lane >> 4) * 8;
    float s = (g == 2) ? 2.0f * kLog2e : -kLog2e;
    const float* src = W_hh + R * 256 + k;
    half8 v;
    #pragma unroll
    for (int j = 0; j < 8; ++j) v[j] = (_Float16)(src[j] * s);
    reinterpret_cast<half8*>(ws)[gid] = v;
}

__device__ __forceinline__ f32x4 mfma16(half8 a, half8 b, f32x4 c) {
    return __builtin_amdgcn_mfma_f32_16x16x32_f16(a, b, c, 0, 0, 0);
}

__global__ __launch_bounds__(256, 1)
void lstm_fused(const float* __restrict__ ts,
                const float* __restrict__ W_ih,
                const float* __restrict__ b_ih,
                const float* __restrict__ b_hh,
                const float* __restrict__ W_out,
                const float* __restrict__ b_out,
                const _Float16* __restrict__ wfrag,
                float* __restrict__ out)
{
    __shared__ __align__(16) _Float16 wlds[65536];      // 128 KB: kt 6,7 frags
    __shared__ __align__(16) _Float16 h_full[16][kHF];  // 8448 B (rows 8..15 stay 0)
    __shared__ __align__(16) float wbl[2048];           // 8 KB: (wih,bias) per (col,gate)

    const int tid  = threadIdx.x;
    const int w    = tid >> 6;      // wave 0..3, owns cols [w*64, w*64+64)
    const int lane = tid & 63;
    const int l16  = lane & 15;
    const int quad = lane >> 4;
    const int bid  = blockIdx.x;    // 0..63
    const int b0   = bid * 8;

    const half8* wf8 = reinterpret_cast<const half8*>(wfrag) + w * 8192;
    half8* wl8 = reinterpret_cast<half8*>(wlds);

    // stage LDS weight tier (kt 6,7 for all subs): dst f = wv*32+c*8+g*2+ktb
    for (int i = tid; i < 8192; i += 256) {
        int ln = i & 63, f = i >> 6;
        int ktb = f & 1, g = (f >> 1) & 3, c = (f >> 3) & 3, wv = (f >> 5) & 3;
        const half8* s8 = reinterpret_cast<const half8*>(wfrag) + wv * 8192;
        wl8[i] = s8[((c * 4 + g) * 8 + 6 + ktb) * 64 + ln];
    }
    // zero h_full (h0 = 0; rows 8..15 permanently 0)
    for (int i = tid; i < 16 * kHF; i += 256) (&h_full[0][0])[i] = (_Float16)0.0f;
    // stage wih/bias table: e = (col*4+g)*2 + which
    for (int e = tid; e < 2048; e += 256) {
        int col = e >> 3, g = (e >> 1) & 3, which = e & 1;
        int R = g * 256 + col;
        float s = (g == 2) ? 2.0f * kLog2e : -kLog2e;
        wbl[e] = which ? (b_ih[R] + b_hh[R]) * s : W_ih[R] * s;
    }

    // ---- AGPR tier: 64 frags (kt 0..3, ALL cp,g) = 256 AGPRs, "+a" pins ----
    half8 wa_[64];
    #pragma unroll
    for (int cp = 0; cp < 4; ++cp)
        #pragma unroll
        for (int g = 0; g < 4; ++g)
            #pragma unroll
            for (int kt = 0; kt < 4; ++kt) {
                int i = cp * 16 + g * 4 + kt;   // 0..63
                wa_[i] = wf8[((cp * 4 + g) * 8 + kt) * 64 + lane];
                asm volatile("" : "+a"(wa_[i]));
            }
    // ---- VGPR tier: 32 frags (kt 4,5) = 128 v, "+v" pins ----
    half8 wv_[32];
    #pragma unroll
    for (int cp = 0; cp < 4; ++cp)
        #pragma unroll
        for (int g = 0; g < 4; ++g)
            #pragma unroll
            for (int ktb = 0; ktb < 2; ++ktb) {
                int i = cp * 8 + g * 2 + ktb;
                wv_[i] = wf8[((cp * 4 + g) * 8 + 4 + ktb) * 64 + lane];
                asm volatile("" : "+v"(wv_[i]));
            }

    float cst[4][4] = {{0.f,0.f,0.f,0.f},{0.f,0.f,0.f,0.f},
                       {0.f,0.f,0.f,0.f},{0.f,0.f,0.f,0.f}};
    float oacc[4]   = {0.f,0.f,0.f,0.f};
    const int colb0 = w * 64 + l16;   // cp=0 column of this lane

    __syncthreads();

    for (int t = 0; t < kT; ++t) {
        // re-pin both tiers (empty asm: constraints only, no code)
        #pragma unroll
        for (int i = 0; i < 64; ++i) asm volatile("" : "+a"(wa_[i]));
        #pragma unroll
        for (int i = 0; i < 32; ++i) asm volatile("" : "+v"(wv_[i]));

        float tsv[4] = {0.f,0.f,0.f,0.f};
        float wo[4]  = {0.f,0.f,0.f,0.f};
        if (quad < 2) {
            #pragma unroll
            for (int r = 0; r < 4; ++r)
                tsv[r] = ts[(b0 + quad * 4 + r) * kT + t];
            #pragma unroll
            for (int cp = 0; cp < 4; ++cp)
                wo[cp] = W_out[t * 256 + colb0 + cp * 16];
        }

        // prefetch all 8 A fragments (shared across cp, g)
        half8 afr[8];
        #pragma unroll
        for (int kt = 0; kt < 8; ++kt)
            afr[kt] = *reinterpret_cast<const half8*>(
                &h_full[l16][kt * 32 + quad * 8]);

        _Float16 hv16[4][4];
        #pragma unroll
        for (int cp = 0; cp < 4; ++cp) {
            f32x4 gacc[4];
            #pragma unroll
            for (int g = 0; g < 4; ++g) { f32x4 z = {0.f,0.f,0.f,0.f}; gacc[g] = z; }
            // r24/r26's exact kt 0..7 order; W(kt) from wa_/wv_/wlds.
            #pragma unroll
            for (int kt = 0; kt < 8; ++kt) {
                #pragma unroll
                for (int g = 0; g < 4; ++g) {
                    half8 wv;
                    if (kt < 4) {
                        wv = wa_[cp * 16 + g * 4 + kt];
                    } else if (kt < 6) {
                        wv = wv_[cp * 8 + g * 2 + (kt - 4)];
                    } else {
                        wv = wl8[(w * 32 + cp * 8 + g * 2 + (kt - 6)) * 64 + lane];
                    }
                    gacc[g] = mfma16(afr[kt], wv, gacc[g]);
                }
            }
            if (quad < 2) {
                const int colb = colb0 + cp * 16;
                f32x2 wb[4];
                #pragma unroll
                for (int g = 0; g < 4; ++g)
                    wb[g] = *reinterpret_cast<const f32x2*>(&wbl[(colb * 4 + g) * 2]);
                #pragma unroll
                for (int r = 0; r < 4; ++r) {
                    float gi = gacc[0][r] + (tsv[r] * wb[0].x + wb[0].y);
                    float gf = gacc[1][r] + (tsv[r] * wb[1].x + wb[1].y);
                    float gg = gacc[2][r] + (tsv[r] * wb[2].x + wb[2].y);
                    float go = gacc[3][r] + (tsv[r] * wb[3].x + wb[3].y);
                    float I = __builtin_amdgcn_rcpf(1.0f + __builtin_amdgcn_exp2f(gi));
                    float F = __builtin_amdgcn_rcpf(1.0f + __builtin_amdgcn_exp2f(gf));
                    float G = 1.0f - 2.0f * __builtin_amdgcn_rcpf(1.0f + __builtin_amdgcn_exp2f(gg));
                    float O = __builtin_amdgcn_rcpf(1.0f + __builtin_amdgcn_exp2f(go));
                    float cn = F * cst[cp][r] + I * G;
                    cst[cp][r] = cn;
                    float tc = 1.0f - 2.0f * __builtin_amdgcn_rcpf(
                                   1.0f + __builtin_amdgcn_exp2f(2.0f * kLog2e * cn));
                    float hv = O * tc;
                    oacc[r] += hv * wo[cp];
                    hv16[cp][r] = (_Float16)hv;
                }
            }
        }
        __syncthreads();   // b1: every wave's A-reads of h_{t-1} are done
        if (quad < 2) {
            #pragma unroll
            for (int cp = 0; cp < 4; ++cp)
                #pragma unroll
                for (int r = 0; r < 4; ++r)
                    h_full[quad * 4 + r][colb0 + cp * 16] = hv16[cp][r];
        }
        __syncthreads();   // b2: h_t complete for next step's A-reads
    }

    // ---- output: reduce oacc over l16 (cols); red overlays dead h_full ----
    float* red = reinterpret_cast<float*>(&h_full[0][0]);
    #pragma unroll
    for (int r = 0; r < 4; ++r) {
        float v = oacc[r];
        v += __shfl_xor(v, 1, 64);
        v += __shfl_xor(v, 2, 64);
        v += __shfl_xor(v, 4, 64);
        v += __shfl_xor(v, 8, 64);
        if (l16 == 0 && quad < 2) red[w * 8 + quad * 4 + r] = v;
    }
    __syncthreads();
    if (tid < 8) {
        float s = b_out[0];
        #pragma unroll
        for (int wv = 0; wv < 4; ++wv) s += red[wv * 8 + tid];
        out[b0 + tid] = s;
    }
}

extern "C" void kernel_launch(void* const* d_in, const int* in_sizes, int n_in,
                              void* d_out, int out_size, void* d_ws, size_t ws_size,
                              hipStream_t stream) {
    const float* ts    = (const float*)d_in[0];
    const float* W_ih  = (const float*)d_in[1];
    const float* W_hh  = (const float*)d_in[2];
    const float* b_ih  = (const float*)d_in[3];
    const float* b_hh  = (const float*)d_in[4];
    const float* W_out = (const float*)d_in[5];
    const float* b_out = (const float*)d_in[6];

    _Float16* wfrag = (_Float16*)d_ws;   // 512 KB; no other workspace, no memset

    prep_weights<<<128, 256, 0, stream>>>(W_hh, wfrag);
    lstm_fused<<<64, 256, 0, stream>>>(ts, W_ih, b_ih, b_hh, W_out, b_out,
                                       wfrag, (float*)d_out);
}